// Round 1
// baseline (1752.899 us; speedup 1.0000x reference)
//
#include <hip/hip_runtime.h>
#include <hip/hip_bf16.h>

#define N_NODES 50000
#define N_EDGES 800000
#define D 64
#define B 64
#define HL 128
#define OUT 32

// ---------------------------------------------------------------------------
// Edge scatter-add: agg[dst] += feat[src].  4 threads... actually 16 threads
// per edge, each thread handles 4 dims via one float4 load + 4 atomics.
// ---------------------------------------------------------------------------
__global__ __launch_bounds__(256) void scatter_kernel(
    const float* __restrict__ feat,   // [N,64]
    const int*   __restrict__ ei,     // [2,E]
    float*       __restrict__ agg)    // [N,64]
{
    long t = (long)blockIdx.x * 256 + threadIdx.x;   // t < E*16
    int e = (int)(t >> 4);
    int g = (int)(t & 15);
    if (e >= N_EDGES) return;
    int s = ei[e];
    int d = ei[N_EDGES + e];
    float4 v = *reinterpret_cast<const float4*>(feat + (size_t)s * D + g * 4);
    float* p = agg + (size_t)d * D + g * 4;
    atomicAdd(p + 0, v.x);
    atomicAdd(p + 1, v.y);
    atomicAdd(p + 2, v.z);
    atomicAdd(p + 3, v.w);
}

// ---------------------------------------------------------------------------
// Per-node GIN MLP: out = relu( relu((x+agg) @ wA.T + bA) @ wB.T + bB )
// One thread per node. h[] / o[] live in registers (static indices only);
// weights are read with wave-uniform indices -> compiler emits s_loads
// (scalar pipe, overlaps VALU FMAs). Second GEMM done as rank-1 updates so
// no runtime-indexed register array is needed.
// out may alias agg (each thread reads its own row fully before writing).
// ---------------------------------------------------------------------------
__global__ __launch_bounds__(256) void gin_mlp_kernel(
    const float* __restrict__ xin,    // [N,64]
    const float*              agg,    // [N,64]
    float*                    outp,   // [N,64]  (may alias agg)
    const float* __restrict__ wA,     // [64,64]
    const float* __restrict__ bA,     // [64]
    const float* __restrict__ wB,     // [64,64]
    const float* __restrict__ bB)     // [64]
{
    int n = blockIdx.x * 256 + threadIdx.x;
    if (n >= N_NODES) return;

    float h[D];
    {
        const float4* x4 = reinterpret_cast<const float4*>(xin + (size_t)n * D);
        const float4* a4 = reinterpret_cast<const float4*>(agg + (size_t)n * D);
#pragma unroll
        for (int i = 0; i < D / 4; ++i) {
            float4 xv = x4[i];
            float4 av = a4[i];
            h[4 * i + 0] = xv.x + av.x;
            h[4 * i + 1] = xv.y + av.y;
            h[4 * i + 2] = xv.z + av.z;
            h[4 * i + 3] = xv.w + av.w;
        }
    }

    float o[D];
#pragma unroll
    for (int k = 0; k < D; ++k) o[k] = bB[k];

#pragma unroll 4
    for (int j = 0; j < D; ++j) {
        float acc = bA[j];
#pragma unroll
        for (int k = 0; k < D; ++k) acc = fmaf(h[k], wA[j * D + k], acc);
        float tj = fmaxf(acc, 0.0f);
#pragma unroll
        for (int k = 0; k < D; ++k) o[k] = fmaf(tj, wB[k * D + j], o[k]);
    }

    float4* o4 = reinterpret_cast<float4*>(outp + (size_t)n * D);
#pragma unroll
    for (int i = 0; i < D / 4; ++i) {
        float4 v;
        v.x = fmaxf(o[4 * i + 0], 0.0f);
        v.y = fmaxf(o[4 * i + 1], 0.0f);
        v.z = fmaxf(o[4 * i + 2], 0.0f);
        v.w = fmaxf(o[4 * i + 3], 0.0f);
        o4[i] = v;
    }
}

// ---------------------------------------------------------------------------
// Global mean pool. batch[] is sorted; one block per graph does two binary
// searches for the segment bounds, then a strided sum. 256 thr = 64 dims x 4.
// ---------------------------------------------------------------------------
__device__ __forceinline__ int lower_bound_dev(const int* a, int n, int v)
{
    int lo = 0, hi = n;
    while (lo < hi) {
        int m = (lo + hi) >> 1;
        if (a[m] < v) lo = m + 1; else hi = m;
    }
    return lo;
}

__global__ __launch_bounds__(256) void pool_kernel(
    const float* __restrict__ feat,   // [N,64]
    const int*   __restrict__ batch,  // [N] sorted
    float*       __restrict__ pooled) // [B,64]
{
    int b = blockIdx.x;
    int start = lower_bound_dev(batch, N_NODES, b);
    int end   = lower_bound_dev(batch, N_NODES, b + 1);

    int d = threadIdx.x & 63;
    int r = threadIdx.x >> 6;    // 0..3

    float acc = 0.0f;
    for (int n = start + r; n < end; n += 4)
        acc += feat[(size_t)n * D + d];

    __shared__ float red[4][D];
    red[r][d] = acc;
    __syncthreads();
    if (r == 0) {
        float s = red[0][d] + red[1][d] + red[2][d] + red[3][d];
        float cnt = (float)(end - start);
        pooled[b * D + d] = s / fmaxf(cnt, 1.0f);
    }
}

// ---------------------------------------------------------------------------
// Head: single-step LSTM + FC + softmax. One block (512 thr) per graph.
// ---------------------------------------------------------------------------
__device__ __forceinline__ float sigmoidf_(float x) { return 1.0f / (1.0f + expf(-x)); }

__global__ __launch_bounds__(512) void head_kernel(
    const float* __restrict__ pooled, // [B,64]
    const float* __restrict__ w_ih,   // [512,64]
    const float* __restrict__ w_hh,   // [512,128]
    const float* __restrict__ b_ih,   // [512]
    const float* __restrict__ b_hh,   // [512]
    const float* __restrict__ fc_w,   // [32,128]
    const float* __restrict__ fc_b,   // [32]
    const float* __restrict__ h0,     // [B,128]
    const float* __restrict__ c0,     // [B,128]
    float*       __restrict__ out_probs, // [B,32]
    float*       __restrict__ out_h1,    // [B,128]
    float*       __restrict__ out_c1)    // [B,128]
{
    int b = blockIdx.x;
    int j = threadIdx.x;   // 0..511

    __shared__ float sp[D];       // pooled row
    __shared__ float sh[HL];      // h0 row
    __shared__ float gates[4 * HL];
    __shared__ float sh1[HL];
    __shared__ float slog[OUT];

    if (j < D) sp[j] = pooled[b * D + j];
    else if (j < D + HL) sh[j - D] = h0[b * HL + (j - D)];
    __syncthreads();

    {
        float acc = b_ih[j] + b_hh[j];
#pragma unroll
        for (int k = 0; k < D; ++k)  acc = fmaf(sp[k], w_ih[j * D + k], acc);
#pragma unroll
        for (int k = 0; k < HL; ++k) acc = fmaf(sh[k], w_hh[j * HL + k], acc);
        gates[j] = acc;
    }
    __syncthreads();

    if (j < HL) {
        float ig = gates[j];
        float fg = gates[HL + j];
        float gg = gates[2 * HL + j];
        float og = gates[3 * HL + j];
        float c  = sigmoidf_(fg) * c0[b * HL + j] + sigmoidf_(ig) * tanhf(gg);
        float hv = sigmoidf_(og) * tanhf(c);
        out_c1[b * HL + j] = c;
        out_h1[b * HL + j] = hv;
        sh1[j] = hv;
    }
    __syncthreads();

    if (j < OUT) {
        float a = fc_b[j];
#pragma unroll
        for (int k = 0; k < HL; ++k) a = fmaf(sh1[k], fc_w[j * HL + k], a);
        slog[j] = a;
    }
    __syncthreads();

    if (j < OUT) {
        float m = -1e30f;
#pragma unroll
        for (int k = 0; k < OUT; ++k) m = fmaxf(m, slog[k]);
        float s = 0.0f;
#pragma unroll
        for (int k = 0; k < OUT; ++k) s += expf(slog[k] - m);
        out_probs[b * OUT + j] = expf(slog[j] - m) / s;
    }
}

// ---------------------------------------------------------------------------
extern "C" void kernel_launch(void* const* d_in, const int* in_sizes, int n_in,
                              void* d_out, int out_size, void* d_ws, size_t ws_size,
                              hipStream_t stream)
{
    const float* x     = (const float*)d_in[0];
    const int*   ei    = (const int*)  d_in[1];
    const int*   batch = (const int*)  d_in[2];
    const float* w1    = (const float*)d_in[3];
    const float* b1    = (const float*)d_in[4];
    const float* w2    = (const float*)d_in[5];
    const float* b2    = (const float*)d_in[6];
    const float* w3    = (const float*)d_in[7];
    const float* b3    = (const float*)d_in[8];
    const float* w4    = (const float*)d_in[9];
    const float* b4    = (const float*)d_in[10];
    const float* w_ih  = (const float*)d_in[11];
    const float* w_hh  = (const float*)d_in[12];
    const float* b_ih  = (const float*)d_in[13];
    const float* b_hh  = (const float*)d_in[14];
    const float* fc_w  = (const float*)d_in[15];
    const float* fc_b  = (const float*)d_in[16];
    const float* h0    = (const float*)d_in[17];
    const float* c0    = (const float*)d_in[18];

    float* buf0   = (float*)d_ws;                       // [N,64] agg / layer2 out
    float* buf1   = buf0 + (size_t)N_NODES * D;         // [N,64] layer1 out
    float* pooled = buf1 + (size_t)N_NODES * D;         // [B,64]

    float* out_probs = (float*)d_out;
    float* out_h1    = out_probs + B * OUT;
    float* out_c1    = out_h1 + B * HL;

    const size_t node_bytes = (size_t)N_NODES * D * sizeof(float);
    const int scatter_blocks = (int)(((long)N_EDGES * 16 + 255) / 256);
    const int mlp_blocks = (N_NODES + 255) / 256;

    // ---- layer 1 ----
    hipMemsetAsync(buf0, 0, node_bytes, stream);
    scatter_kernel<<<scatter_blocks, 256, 0, stream>>>(x, ei, buf0);
    gin_mlp_kernel<<<mlp_blocks, 256, 0, stream>>>(x, buf0, buf1, w1, b1, w2, b2);

    // ---- layer 2 ----
    hipMemsetAsync(buf0, 0, node_bytes, stream);
    scatter_kernel<<<scatter_blocks, 256, 0, stream>>>(buf1, ei, buf0);
    gin_mlp_kernel<<<mlp_blocks, 256, 0, stream>>>(buf1, buf0, buf0, w3, b3, w4, b4);

    // ---- pool + head ----
    pool_kernel<<<B, 256, 0, stream>>>(buf0, batch, pooled);
    head_kernel<<<B, 512, 0, stream>>>(pooled, w_ih, w_hh, b_ih, b_hh,
                                       fc_w, fc_b, h0, c0,
                                       out_probs, out_h1, out_c1);
}

// Round 2
// 659.965 us; speedup vs baseline: 2.6560x; 2.6560x over previous
//
#include <hip/hip_runtime.h>
#include <hip/hip_bf16.h>

#define N_NODES 50000
#define N_EDGES 800000
#define D 64
#define B 64
#define HL 128
#define OUT 32

#define NPAD 50016   // padded (N_NODES+1) for alignment

// ---------------------------------------------------------------------------
// CSR build step 1: in-degree histogram (int atomics; 800k ops over 50k ctrs)
// ---------------------------------------------------------------------------
__global__ __launch_bounds__(256) void hist_kernel(
    const int* __restrict__ ei, int* __restrict__ deg)
{
    int e = blockIdx.x * 256 + threadIdx.x;
    if (e < N_EDGES) atomicAdd(&deg[ei[N_EDGES + e]], 1);
}

// ---------------------------------------------------------------------------
// CSR build step 2: exclusive prefix sum over deg -> offs[0..N].
// Single 1024-thread block, Hillis-Steele per 1024-chunk with running carry.
// ---------------------------------------------------------------------------
__global__ __launch_bounds__(1024) void scan_kernel(
    const int* __restrict__ deg, int* __restrict__ offs)
{
    __shared__ int buf[1024];
    __shared__ int carry_s;
    int t = threadIdx.x;
    if (t == 0) { carry_s = 0; offs[0] = 0; }
    __syncthreads();
    for (int base = 0; base < N_NODES; base += 1024) {
        int i = base + t;
        int v = (i < N_NODES) ? deg[i] : 0;
        buf[t] = v;
        __syncthreads();
        for (int off = 1; off < 1024; off <<= 1) {
            int add = (t >= off) ? buf[t - off] : 0;
            __syncthreads();
            buf[t] += add;
            __syncthreads();
        }
        int incl = buf[t] + carry_s;
        if (i < N_NODES) offs[i + 1] = incl;
        __syncthreads();
        if (t == 1023) carry_s = incl;
        __syncthreads();
    }
}

__global__ __launch_bounds__(256) void copy_kernel(
    const int* __restrict__ offs, int* __restrict__ cursor)
{
    int i = blockIdx.x * 256 + threadIdx.x;
    if (i < N_NODES) cursor[i] = offs[i];
}

// ---------------------------------------------------------------------------
// CSR build step 3: place src ids (int atomics on per-node cursors)
// ---------------------------------------------------------------------------
__global__ __launch_bounds__(256) void fill_kernel(
    const int* __restrict__ ei, int* __restrict__ cursor, int* __restrict__ csr)
{
    int e = blockIdx.x * 256 + threadIdx.x;
    if (e >= N_EDGES) return;
    int s = ei[e];
    int d = ei[N_EDGES + e];
    int p = atomicAdd(&cursor[d], 1);
    csr[p] = s;
}

// ---------------------------------------------------------------------------
// Gather aggregation, fused with the GIN "+x": out[n] = x[n] + sum_j feat[j].
// One wave per node; lane = feature dim; each neighbor read is a fully
// coalesced 256B line. 2-edge unroll for load-level ILP.
// ---------------------------------------------------------------------------
__global__ __launch_bounds__(256) void gather_kernel(
    const float* __restrict__ feat,   // [N,64] neighbor features
    const float* __restrict__ xin,    // [N,64] self features (same buf ok)
    const int*   __restrict__ offs,   // [N+1]
    const int*   __restrict__ csr,    // [E]
    float*       __restrict__ outp)   // [N,64]
{
    int n = blockIdx.x * 4 + (threadIdx.x >> 6);
    int lane = threadIdx.x & 63;
    if (n >= N_NODES) return;
    int s0 = offs[n], s1 = offs[n + 1];
    float acc = xin[(size_t)n * D + lane];
    int e = s0;
    for (; e + 1 < s1; e += 2) {
        int a = csr[e];
        int c = csr[e + 1];
        float va = feat[(size_t)a * D + lane];
        float vc = feat[(size_t)c * D + lane];
        acc += va + vc;
    }
    if (e < s1) acc += feat[(size_t)csr[e] * D + lane];
    outp[(size_t)n * D + lane] = acc;
}

// ---------------------------------------------------------------------------
// Per-node GIN MLP on pre-summed h: out = relu( relu(h@wA.T+bA) @ wB.T + bB )
// One thread per node; weights via wave-uniform s_loads; 2nd GEMM as rank-1
// updates (static register indices). outp may alias hin.
// ---------------------------------------------------------------------------
__global__ __launch_bounds__(256) void gin_mlp_kernel(
    const float*              hin,    // [N,64]
    float*                    outp,   // [N,64]
    const float* __restrict__ wA,     // [64,64]
    const float* __restrict__ bA,     // [64]
    const float* __restrict__ wB,     // [64,64]
    const float* __restrict__ bB)     // [64]
{
    int n = blockIdx.x * 256 + threadIdx.x;
    if (n >= N_NODES) return;

    float h[D];
    {
        const float4* h4 = reinterpret_cast<const float4*>(hin + (size_t)n * D);
#pragma unroll
        for (int i = 0; i < D / 4; ++i) {
            float4 hv = h4[i];
            h[4 * i + 0] = hv.x;
            h[4 * i + 1] = hv.y;
            h[4 * i + 2] = hv.z;
            h[4 * i + 3] = hv.w;
        }
    }

    float o[D];
#pragma unroll
    for (int k = 0; k < D; ++k) o[k] = bB[k];

#pragma unroll 4
    for (int j = 0; j < D; ++j) {
        float acc = bA[j];
#pragma unroll
        for (int k = 0; k < D; ++k) acc = fmaf(h[k], wA[j * D + k], acc);
        float tj = fmaxf(acc, 0.0f);
#pragma unroll
        for (int k = 0; k < D; ++k) o[k] = fmaf(tj, wB[k * D + j], o[k]);
    }

    float4* o4 = reinterpret_cast<float4*>(outp + (size_t)n * D);
#pragma unroll
    for (int i = 0; i < D / 4; ++i) {
        float4 v;
        v.x = fmaxf(o[4 * i + 0], 0.0f);
        v.y = fmaxf(o[4 * i + 1], 0.0f);
        v.z = fmaxf(o[4 * i + 2], 0.0f);
        v.w = fmaxf(o[4 * i + 3], 0.0f);
        o4[i] = v;
    }
}

// ---------------------------------------------------------------------------
// Global mean pool over sorted batch[].
// ---------------------------------------------------------------------------
__device__ __forceinline__ int lower_bound_dev(const int* a, int n, int v)
{
    int lo = 0, hi = n;
    while (lo < hi) {
        int m = (lo + hi) >> 1;
        if (a[m] < v) lo = m + 1; else hi = m;
    }
    return lo;
}

__global__ __launch_bounds__(256) void pool_kernel(
    const float* __restrict__ feat,
    const int*   __restrict__ batch,
    float*       __restrict__ pooled)
{
    int b = blockIdx.x;
    int start = lower_bound_dev(batch, N_NODES, b);
    int end   = lower_bound_dev(batch, N_NODES, b + 1);

    int d = threadIdx.x & 63;
    int r = threadIdx.x >> 6;

    float acc = 0.0f;
    for (int n = start + r; n < end; n += 4)
        acc += feat[(size_t)n * D + d];

    __shared__ float red[4][D];
    red[r][d] = acc;
    __syncthreads();
    if (r == 0) {
        float s = red[0][d] + red[1][d] + red[2][d] + red[3][d];
        float cnt = (float)(end - start);
        pooled[b * D + d] = s / fmaxf(cnt, 1.0f);
    }
}

// ---------------------------------------------------------------------------
// Head: single-step LSTM + FC + softmax. One block (512 thr) per graph.
// ---------------------------------------------------------------------------
__device__ __forceinline__ float sigmoidf_(float x) { return 1.0f / (1.0f + expf(-x)); }

__global__ __launch_bounds__(512) void head_kernel(
    const float* __restrict__ pooled,
    const float* __restrict__ w_ih,
    const float* __restrict__ w_hh,
    const float* __restrict__ b_ih,
    const float* __restrict__ b_hh,
    const float* __restrict__ fc_w,
    const float* __restrict__ fc_b,
    const float* __restrict__ h0,
    const float* __restrict__ c0,
    float*       __restrict__ out_probs,
    float*       __restrict__ out_h1,
    float*       __restrict__ out_c1)
{
    int b = blockIdx.x;
    int j = threadIdx.x;

    __shared__ float sp[D];
    __shared__ float sh[HL];
    __shared__ float gates[4 * HL];
    __shared__ float sh1[HL];
    __shared__ float slog[OUT];

    if (j < D) sp[j] = pooled[b * D + j];
    else if (j < D + HL) sh[j - D] = h0[b * HL + (j - D)];
    __syncthreads();

    {
        float acc = b_ih[j] + b_hh[j];
#pragma unroll
        for (int k = 0; k < D; ++k)  acc = fmaf(sp[k], w_ih[j * D + k], acc);
#pragma unroll
        for (int k = 0; k < HL; ++k) acc = fmaf(sh[k], w_hh[j * HL + k], acc);
        gates[j] = acc;
    }
    __syncthreads();

    if (j < HL) {
        float ig = gates[j];
        float fg = gates[HL + j];
        float gg = gates[2 * HL + j];
        float og = gates[3 * HL + j];
        float c  = sigmoidf_(fg) * c0[b * HL + j] + sigmoidf_(ig) * tanhf(gg);
        float hv = sigmoidf_(og) * tanhf(c);
        out_c1[b * HL + j] = c;
        out_h1[b * HL + j] = hv;
        sh1[j] = hv;
    }
    __syncthreads();

    if (j < OUT) {
        float a = fc_b[j];
#pragma unroll
        for (int k = 0; k < HL; ++k) a = fmaf(sh1[k], fc_w[j * HL + k], a);
        slog[j] = a;
    }
    __syncthreads();

    if (j < OUT) {
        float m = -1e30f;
#pragma unroll
        for (int k = 0; k < OUT; ++k) m = fmaxf(m, slog[k]);
        float s = 0.0f;
#pragma unroll
        for (int k = 0; k < OUT; ++k) s += expf(slog[k] - m);
        out_probs[b * OUT + j] = expf(slog[j] - m) / s;
    }
}

// ---------------------------------------------------------------------------
extern "C" void kernel_launch(void* const* d_in, const int* in_sizes, int n_in,
                              void* d_out, int out_size, void* d_ws, size_t ws_size,
                              hipStream_t stream)
{
    const float* x     = (const float*)d_in[0];
    const int*   ei    = (const int*)  d_in[1];
    const int*   batch = (const int*)  d_in[2];
    const float* w1    = (const float*)d_in[3];
    const float* b1    = (const float*)d_in[4];
    const float* w2    = (const float*)d_in[5];
    const float* b2    = (const float*)d_in[6];
    const float* w3    = (const float*)d_in[7];
    const float* b3    = (const float*)d_in[8];
    const float* w4    = (const float*)d_in[9];
    const float* b4    = (const float*)d_in[10];
    const float* w_ih  = (const float*)d_in[11];
    const float* w_hh  = (const float*)d_in[12];
    const float* b_ih  = (const float*)d_in[13];
    const float* b_hh  = (const float*)d_in[14];
    const float* fc_w  = (const float*)d_in[15];
    const float* fc_b  = (const float*)d_in[16];
    const float* h0    = (const float*)d_in[17];
    const float* c0    = (const float*)d_in[18];

    // workspace layout (ints first, 16B-aligned float region after)
    int* deg    = (int*)d_ws;            // NPAD
    int* offs   = deg + NPAD;            // NPAD (uses N_NODES+1)
    int* cursor = offs + NPAD;           // NPAD
    int* csr    = cursor + NPAD;         // N_EDGES
    float* buf0   = (float*)(csr + N_EDGES);          // [N,64]
    float* buf1   = buf0 + (size_t)N_NODES * D;       // [N,64]
    float* pooled = buf1 + (size_t)N_NODES * D;       // [B,64]

    float* out_probs = (float*)d_out;
    float* out_h1    = out_probs + B * OUT;
    float* out_c1    = out_h1 + B * HL;

    const int eb = (N_EDGES + 255) / 256;       // 3125
    const int nb = (N_NODES + 255) / 256;       // 196
    const int gb = (N_NODES + 3) / 4;           // 12500

    // ---- CSR build (dst-indexed) ----
    hipMemsetAsync(deg, 0, NPAD * sizeof(int), stream);
    hist_kernel<<<eb, 256, 0, stream>>>(ei, deg);
    scan_kernel<<<1, 1024, 0, stream>>>(deg, offs);
    copy_kernel<<<nb, 256, 0, stream>>>(offs, cursor);
    fill_kernel<<<eb, 256, 0, stream>>>(ei, cursor, csr);

    // ---- layer 1 ----
    gather_kernel<<<gb, 256, 0, stream>>>(x, x, offs, csr, buf0);
    gin_mlp_kernel<<<nb, 256, 0, stream>>>(buf0, buf1, w1, b1, w2, b2);

    // ---- layer 2 ----
    gather_kernel<<<gb, 256, 0, stream>>>(buf1, buf1, offs, csr, buf0);
    gin_mlp_kernel<<<nb, 256, 0, stream>>>(buf0, buf0, w3, b3, w4, b4);

    // ---- pool + head ----
    pool_kernel<<<B, 256, 0, stream>>>(buf0, batch, pooled);
    head_kernel<<<B, 512, 0, stream>>>(pooled, w_ih, w_hh, b_ih, b_hh,
                                       fc_w, fc_b, h0, c0,
                                       out_probs, out_h1, out_c1);
}

// Round 3
// 504.111 us; speedup vs baseline: 3.4772x; 1.3092x over previous
//
#include <hip/hip_runtime.h>
#include <hip/hip_bf16.h>

#define N_NODES 50000
#define N_EDGES 800000
#define D 64
#define B 64
#define HL 128
#define OUT 32

#define NPAD 50016   // padded (N_NODES+1) for alignment

// ---------------------------------------------------------------------------
// CSR build step 1: in-degree histogram (int atomics; 800k ops over 50k ctrs)
// ---------------------------------------------------------------------------
__global__ __launch_bounds__(256) void hist_kernel(
    const int* __restrict__ ei, int* __restrict__ deg)
{
    int e = blockIdx.x * 256 + threadIdx.x;
    if (e < N_EDGES) atomicAdd(&deg[ei[N_EDGES + e]], 1);
}

// ---------------------------------------------------------------------------
// CSR build step 2: exclusive prefix sum over deg -> offs[0..N].
// Single 1024-thread block, Hillis-Steele per 1024-chunk with running carry.
// ---------------------------------------------------------------------------
__global__ __launch_bounds__(1024) void scan_kernel(
    const int* __restrict__ deg, int* __restrict__ offs)
{
    __shared__ int buf[1024];
    __shared__ int carry_s;
    int t = threadIdx.x;
    if (t == 0) { carry_s = 0; offs[0] = 0; }
    __syncthreads();
    for (int base = 0; base < N_NODES; base += 1024) {
        int i = base + t;
        int v = (i < N_NODES) ? deg[i] : 0;
        buf[t] = v;
        __syncthreads();
        for (int off = 1; off < 1024; off <<= 1) {
            int add = (t >= off) ? buf[t - off] : 0;
            __syncthreads();
            buf[t] += add;
            __syncthreads();
        }
        int incl = buf[t] + carry_s;
        if (i < N_NODES) offs[i + 1] = incl;
        __syncthreads();
        if (t == 1023) carry_s = incl;
        __syncthreads();
    }
}

__global__ __launch_bounds__(256) void copy_kernel(
    const int* __restrict__ offs, int* __restrict__ cursor)
{
    int i = blockIdx.x * 256 + threadIdx.x;
    if (i < N_NODES) cursor[i] = offs[i];
}

// ---------------------------------------------------------------------------
// CSR build step 3: place src ids (int atomics on per-node cursors)
// ---------------------------------------------------------------------------
__global__ __launch_bounds__(256) void fill_kernel(
    const int* __restrict__ ei, int* __restrict__ cursor, int* __restrict__ csr)
{
    int e = blockIdx.x * 256 + threadIdx.x;
    if (e >= N_EDGES) return;
    int s = ei[e];
    int d = ei[N_EDGES + e];
    int p = atomicAdd(&cursor[d], 1);
    csr[p] = s;
}

// ---------------------------------------------------------------------------
// Fused GIN layer: out = relu( relu((x + sum_nbr x) @ wA.T + bA) @ wB.T + bB )
// Wave per node (lane = feature dim). Weights staged TRANSPOSED in LDS with
// +1 padding: read addr = k*65+lane -> bank (k+lane)%32, 2-way max (free).
// h / t broadcast via LDS same-address reads (conflict-free broadcast).
// Each wave processes 4 consecutive nodes to amortize weight staging.
// ---------------------------------------------------------------------------
__global__ __launch_bounds__(256) void gin_layer_kernel(
    const float* __restrict__ feat,   // [N,64] (self + neighbor features)
    const int*   __restrict__ offs,   // [N+1]
    const int*   __restrict__ csr,    // [E]
    const float* __restrict__ wA,     // [64,64]
    const float* __restrict__ bA,     // [64]
    const float* __restrict__ wB,     // [64,64]
    const float* __restrict__ bB,     // [64]
    float*       __restrict__ outp)   // [N,64]
{
    __shared__ float sWA[D][D + 1];   // sWA[k][j] = wA[j][k]
    __shared__ float sWB[D][D + 1];   // sWB[j][k] = wB[k][j]
    __shared__ float sh[4][D];        // h broadcast per wave
    __shared__ float st[4][D];        // t broadcast per wave

    const int tid  = threadIdx.x;
    const int w    = tid >> 6;        // wave 0..3
    const int lane = tid & 63;

    // lane-indexed biases (loop-invariant)
    const float bAl = bA[lane];
    const float bBl = bB[lane];

    // stage weights transposed; global reads coalesced, LDS writes stride-65
#pragma unroll
    for (int i = 0; i < D * D / 256; ++i) {
        int idx = tid + i * 256;
        int r = idx >> 6, c = idx & 63;
        sWA[c][r] = wA[idx];          // sWA[k][j] = wA[j*64+k]
        sWB[c][r] = wB[idx];          // sWB[j][k] = wB[k*64+j]
    }
    __syncthreads();

#pragma unroll
    for (int i = 0; i < 4; ++i) {
        int n = (blockIdx.x * 4 + w) * 4 + i;   // 4 consecutive nodes per wave
        if (n >= N_NODES) continue;

        // ---- gather: acc = x[n] + sum_{j in N(n)} x[j], lane = dim ----
        int s0 = offs[n], s1 = offs[n + 1];
        float acc = feat[(size_t)n * D + lane];
        int e = s0;
        for (; e + 3 < s1; e += 4) {
            int a0 = csr[e], a1 = csr[e + 1], a2 = csr[e + 2], a3 = csr[e + 3];
            float v0 = feat[(size_t)a0 * D + lane];
            float v1 = feat[(size_t)a1 * D + lane];
            float v2 = feat[(size_t)a2 * D + lane];
            float v3 = feat[(size_t)a3 * D + lane];
            acc += (v0 + v1) + (v2 + v3);
        }
        for (; e < s1; ++e) acc += feat[(size_t)csr[e] * D + lane];

        sh[w][lane] = acc;   // same-wave LDS write->read, no barrier needed

        // ---- GEMM 1: t_lane = relu(bA + sum_k h[k] * wA[lane][k]) ----
        float t0 = bAl, t1 = 0.0f;
#pragma unroll
        for (int k = 0; k < D; k += 2) {
            t0 = fmaf(sh[w][k],     sWA[k][lane],     t0);
            t1 = fmaf(sh[w][k + 1], sWA[k + 1][lane], t1);
        }
        float t = fmaxf(t0 + t1, 0.0f);
        st[w][lane] = t;

        // ---- GEMM 2: o_lane = relu(bB + sum_j t[j] * wB[lane][j]) ----
        float o0 = bBl, o1 = 0.0f;
#pragma unroll
        for (int j = 0; j < D; j += 2) {
            o0 = fmaf(st[w][j],     sWB[j][lane],     o0);
            o1 = fmaf(st[w][j + 1], sWB[j + 1][lane], o1);
        }
        outp[(size_t)n * D + lane] = fmaxf(o0 + o1, 0.0f);
    }
}

// ---------------------------------------------------------------------------
// Global mean pool over sorted batch[].
// ---------------------------------------------------------------------------
__device__ __forceinline__ int lower_bound_dev(const int* a, int n, int v)
{
    int lo = 0, hi = n;
    while (lo < hi) {
        int m = (lo + hi) >> 1;
        if (a[m] < v) lo = m + 1; else hi = m;
    }
    return lo;
}

__global__ __launch_bounds__(256) void pool_kernel(
    const float* __restrict__ feat,
    const int*   __restrict__ batch,
    float*       __restrict__ pooled)
{
    int b = blockIdx.x;
    int start = lower_bound_dev(batch, N_NODES, b);
    int end   = lower_bound_dev(batch, N_NODES, b + 1);

    int d = threadIdx.x & 63;
    int r = threadIdx.x >> 6;

    float acc = 0.0f;
    for (int n = start + r; n < end; n += 4)
        acc += feat[(size_t)n * D + d];

    __shared__ float red[4][D];
    red[r][d] = acc;
    __syncthreads();
    if (r == 0) {
        float s = red[0][d] + red[1][d] + red[2][d] + red[3][d];
        float cnt = (float)(end - start);
        pooled[b * D + d] = s / fmaxf(cnt, 1.0f);
    }
}

// ---------------------------------------------------------------------------
// Head: single-step LSTM + FC + softmax. One block (512 thr) per graph.
// ---------------------------------------------------------------------------
__device__ __forceinline__ float sigmoidf_(float x) { return 1.0f / (1.0f + expf(-x)); }

__global__ __launch_bounds__(512) void head_kernel(
    const float* __restrict__ pooled,
    const float* __restrict__ w_ih,
    const float* __restrict__ w_hh,
    const float* __restrict__ b_ih,
    const float* __restrict__ b_hh,
    const float* __restrict__ fc_w,
    const float* __restrict__ fc_b,
    const float* __restrict__ h0,
    const float* __restrict__ c0,
    float*       __restrict__ out_probs,
    float*       __restrict__ out_h1,
    float*       __restrict__ out_c1)
{
    int b = blockIdx.x;
    int j = threadIdx.x;

    __shared__ float sp[D];
    __shared__ float sh[HL];
    __shared__ float gates[4 * HL];
    __shared__ float sh1[HL];
    __shared__ float slog[OUT];

    if (j < D) sp[j] = pooled[b * D + j];
    else if (j < D + HL) sh[j - D] = h0[b * HL + (j - D)];
    __syncthreads();

    {
        float acc = b_ih[j] + b_hh[j];
#pragma unroll
        for (int k = 0; k < D; ++k)  acc = fmaf(sp[k], w_ih[j * D + k], acc);
#pragma unroll
        for (int k = 0; k < HL; ++k) acc = fmaf(sh[k], w_hh[j * HL + k], acc);
        gates[j] = acc;
    }
    __syncthreads();

    if (j < HL) {
        float ig = gates[j];
        float fg = gates[HL + j];
        float gg = gates[2 * HL + j];
        float og = gates[3 * HL + j];
        float c  = sigmoidf_(fg) * c0[b * HL + j] + sigmoidf_(ig) * tanhf(gg);
        float hv = sigmoidf_(og) * tanhf(c);
        out_c1[b * HL + j] = c;
        out_h1[b * HL + j] = hv;
        sh1[j] = hv;
    }
    __syncthreads();

    if (j < OUT) {
        float a = fc_b[j];
#pragma unroll
        for (int k = 0; k < HL; ++k) a = fmaf(sh1[k], fc_w[j * HL + k], a);
        slog[j] = a;
    }
    __syncthreads();

    if (j < OUT) {
        float m = -1e30f;
#pragma unroll
        for (int k = 0; k < OUT; ++k) m = fmaxf(m, slog[k]);
        float s = 0.0f;
#pragma unroll
        for (int k = 0; k < OUT; ++k) s += expf(slog[k] - m);
        out_probs[b * OUT + j] = expf(slog[j] - m) / s;
    }
}

// ---------------------------------------------------------------------------
extern "C" void kernel_launch(void* const* d_in, const int* in_sizes, int n_in,
                              void* d_out, int out_size, void* d_ws, size_t ws_size,
                              hipStream_t stream)
{
    const float* x     = (const float*)d_in[0];
    const int*   ei    = (const int*)  d_in[1];
    const int*   batch = (const int*)  d_in[2];
    const float* w1    = (const float*)d_in[3];
    const float* b1    = (const float*)d_in[4];
    const float* w2    = (const float*)d_in[5];
    const float* b2    = (const float*)d_in[6];
    const float* w3    = (const float*)d_in[7];
    const float* b3    = (const float*)d_in[8];
    const float* w4    = (const float*)d_in[9];
    const float* b4    = (const float*)d_in[10];
    const float* w_ih  = (const float*)d_in[11];
    const float* w_hh  = (const float*)d_in[12];
    const float* b_ih  = (const float*)d_in[13];
    const float* b_hh  = (const float*)d_in[14];
    const float* fc_w  = (const float*)d_in[15];
    const float* fc_b  = (const float*)d_in[16];
    const float* h0    = (const float*)d_in[17];
    const float* c0    = (const float*)d_in[18];

    // workspace layout (ints first, 16B-aligned float region after)
    int* deg    = (int*)d_ws;            // NPAD
    int* offs   = deg + NPAD;            // NPAD (uses N_NODES+1)
    int* cursor = offs + NPAD;           // NPAD
    int* csr    = cursor + NPAD;         // N_EDGES
    float* buf0   = (float*)(csr + N_EDGES);          // [N,64]
    float* buf1   = buf0 + (size_t)N_NODES * D;       // [N,64]
    float* pooled = buf1 + (size_t)N_NODES * D;       // [B,64]

    float* out_probs = (float*)d_out;
    float* out_h1    = out_probs + B * OUT;
    float* out_c1    = out_h1 + B * HL;

    const int eb = (N_EDGES + 255) / 256;       // 3125
    const int nb = (N_NODES + 255) / 256;       // 196
    const int lb = (N_NODES + 15) / 16;         // 3125 (16 nodes per block)

    // ---- CSR build (dst-indexed) ----
    hipMemsetAsync(deg, 0, NPAD * sizeof(int), stream);
    hist_kernel<<<eb, 256, 0, stream>>>(ei, deg);
    scan_kernel<<<1, 1024, 0, stream>>>(deg, offs);
    copy_kernel<<<nb, 256, 0, stream>>>(offs, cursor);
    fill_kernel<<<eb, 256, 0, stream>>>(ei, cursor, csr);

    // ---- layer 1 (fused gather + MLP) ----
    gin_layer_kernel<<<lb, 256, 0, stream>>>(x, offs, csr, w1, b1, w2, b2, buf1);

    // ---- layer 2 ----
    gin_layer_kernel<<<lb, 256, 0, stream>>>(buf1, offs, csr, w3, b3, w4, b4, buf0);

    // ---- pool + head ----
    pool_kernel<<<B, 256, 0, stream>>>(buf0, batch, pooled);
    head_kernel<<<B, 512, 0, stream>>>(pooled, w_ih, w_hh, b_ih, b_hh,
                                       fc_w, fc_b, h0, c0,
                                       out_probs, out_h1, out_c1);
}

// Round 4
// 421.165 us; speedup vs baseline: 4.1620x; 1.1969x over previous
//
#include <hip/hip_runtime.h>
#include <hip/hip_bf16.h>

#define N_NODES 50000
#define N_EDGES 800000
#define D 64
#define B 64
#define HL 128
#define OUT 32

#define NPAD 50016      // padded (N_NODES+1) for alignment
#define NB 196          // ceil(N_NODES/256)
#define WPAD 68         // weight row stride in LDS: 272B = 16B-aligned, banks spread

// ---------------------------------------------------------------------------
// CSR build step 1: in-degree histogram (int atomics; 800k ops over 50k ctrs)
// ---------------------------------------------------------------------------
__global__ __launch_bounds__(256) void hist_kernel(
    const int* __restrict__ ei, int* __restrict__ deg)
{
    int e = blockIdx.x * 256 + threadIdx.x;
    if (e < N_EDGES) atomicAdd(&deg[ei[N_EDGES + e]], 1);
}

// ---------------------------------------------------------------------------
// 3-phase parallel exclusive scan of deg[50000] -> offs[0..N], cursor[i]=offs[i]
// ---------------------------------------------------------------------------
__global__ __launch_bounds__(256) void scan_a_kernel(    // per-block sums
    const int* __restrict__ deg, int* __restrict__ bsum)
{
    int i = blockIdx.x * 256 + threadIdx.x;
    int v = (i < N_NODES) ? deg[i] : 0;
#pragma unroll
    for (int off = 32; off >= 1; off >>= 1) v += __shfl_down(v, off, 64);
    __shared__ int ws[4];
    int w = threadIdx.x >> 6, lane = threadIdx.x & 63;
    if (lane == 0) ws[w] = v;
    __syncthreads();
    if (threadIdx.x == 0) bsum[blockIdx.x] = ws[0] + ws[1] + ws[2] + ws[3];
}

__global__ __launch_bounds__(256) void scan_b_kernel(    // scan the 196 block sums
    const int* __restrict__ bsum, int* __restrict__ bpre)
{
    __shared__ int buf[256];
    int t = threadIdx.x;
    int v = (t < NB) ? bsum[t] : 0;
    buf[t] = v;
    __syncthreads();
    for (int off = 1; off < 256; off <<= 1) {
        int add = (t >= off) ? buf[t - off] : 0;
        __syncthreads();
        buf[t] += add;
        __syncthreads();
    }
    if (t < NB) bpre[t] = buf[t] - v;   // exclusive
}

__global__ __launch_bounds__(256) void scan_c_kernel(    // local scan + base
    const int* __restrict__ deg, const int* __restrict__ bpre,
    int* __restrict__ offs, int* __restrict__ cursor)
{
    __shared__ int buf[256];
    int t = threadIdx.x;
    int i = blockIdx.x * 256 + t;
    int v = (i < N_NODES) ? deg[i] : 0;
    buf[t] = v;
    __syncthreads();
    for (int off = 1; off < 256; off <<= 1) {
        int add = (t >= off) ? buf[t - off] : 0;
        __syncthreads();
        buf[t] += add;
        __syncthreads();
    }
    int incl = buf[t] + bpre[blockIdx.x];
    if (i < N_NODES) {
        offs[i + 1] = incl;
        cursor[i]   = incl - v;   // exclusive prefix = fill cursor start
    }
    if (i == 0) offs[0] = 0;
}

// ---------------------------------------------------------------------------
// CSR build step 3: place src ids (int atomics on per-node cursors)
// ---------------------------------------------------------------------------
__global__ __launch_bounds__(256) void fill_kernel(
    const int* __restrict__ ei, int* __restrict__ cursor, int* __restrict__ csr)
{
    int e = blockIdx.x * 256 + threadIdx.x;
    if (e >= N_EDGES) return;
    int s = ei[e];
    int d = ei[N_EDGES + e];
    int p = atomicAdd(&cursor[d], 1);
    csr[p] = s;
}

// ---------------------------------------------------------------------------
// Fused GIN layer: out = relu( relu((x + sum_nbr x) @ wA.T + bA) @ wB.T + bB )
// Wave per node (lane = out dim). Weights row-major in LDS with row stride 68
// (272B: 16B-aligned; lane row bases spread over all 32 banks) -> per-lane
// ds_read_b128 row reads at the data-volume floor. h / t broadcast via
// same-address b128 reads (conflict-free). 4 accumulator chains for ILP.
// ---------------------------------------------------------------------------
__global__ __launch_bounds__(256) void gin_layer_kernel(
    const float* __restrict__ feat,   // [N,64]
    const int*   __restrict__ offs,   // [N+1]
    const int*   __restrict__ csr,    // [E]
    const float* __restrict__ wA,     // [64,64]
    const float* __restrict__ bA,     // [64]
    const float* __restrict__ wB,     // [64,64]
    const float* __restrict__ bB,     // [64]
    float*       __restrict__ outp)   // [N,64]
{
    __shared__ float sWA[D][WPAD];    // sWA[j][k] = wA[j][k]
    __shared__ float sWB[D][WPAD];    // sWB[k][j] = wB[k][j]
    __shared__ float sh[4][D];        // gathered h per wave
    __shared__ float st[4][D];        // relu(h@wA.T+bA) per wave

    const int tid  = threadIdx.x;
    const int w    = tid >> 6;
    const int lane = tid & 63;

    const float bAl = bA[lane];
    const float bBl = bB[lane];

    // stage weights row-major (global coalesced, LDS 2-way max = free)
#pragma unroll
    for (int i = 0; i < D * D / 256; ++i) {
        int idx = tid + i * 256;
        int r = idx >> 6, c = idx & 63;
        sWA[r][c] = wA[idx];
        sWB[r][c] = wB[idx];
    }
    __syncthreads();

    const float4* wArow = reinterpret_cast<const float4*>(&sWA[lane][0]);
    const float4* wBrow = reinterpret_cast<const float4*>(&sWB[lane][0]);
    const float4* hrow  = reinterpret_cast<const float4*>(&sh[w][0]);
    const float4* trow  = reinterpret_cast<const float4*>(&st[w][0]);

#pragma unroll
    for (int i = 0; i < 4; ++i) {
        int n = (blockIdx.x * 4 + w) * 4 + i;   // 4 consecutive nodes per wave
        if (n >= N_NODES) continue;

        // ---- gather: acc = x[n] + sum_{j in N(n)} x[j], lane = dim ----
        int s0 = offs[n], s1 = offs[n + 1];
        float acc = feat[(size_t)n * D + lane];
        int e = s0;
        for (; e + 3 < s1; e += 4) {
            int a0 = csr[e], a1 = csr[e + 1], a2 = csr[e + 2], a3 = csr[e + 3];
            float v0 = feat[(size_t)a0 * D + lane];
            float v1 = feat[(size_t)a1 * D + lane];
            float v2 = feat[(size_t)a2 * D + lane];
            float v3 = feat[(size_t)a3 * D + lane];
            acc += (v0 + v1) + (v2 + v3);
        }
        for (; e < s1; ++e) acc += feat[(size_t)csr[e] * D + lane];

        sh[w][lane] = acc;   // same-wave LDS write->read (compiler waits lgkm)

        // ---- GEMM 1: t_lane = relu(bA + sum_k h[k] * wA[lane][k]) ----
        float t0 = bAl, t1 = 0.0f, t2 = 0.0f, t3 = 0.0f;
#pragma unroll
        for (int k4 = 0; k4 < D / 4; ++k4) {
            float4 hv = hrow[k4];
            float4 wv = wArow[k4];
            t0 = fmaf(hv.x, wv.x, t0);
            t1 = fmaf(hv.y, wv.y, t1);
            t2 = fmaf(hv.z, wv.z, t2);
            t3 = fmaf(hv.w, wv.w, t3);
        }
        float t = fmaxf((t0 + t1) + (t2 + t3), 0.0f);
        st[w][lane] = t;

        // ---- GEMM 2: o_lane = relu(bB + sum_j t[j] * wB[lane][j]) ----
        float o0 = bBl, o1 = 0.0f, o2 = 0.0f, o3 = 0.0f;
#pragma unroll
        for (int j4 = 0; j4 < D / 4; ++j4) {
            float4 tv = trow[j4];
            float4 wv = wBrow[j4];
            o0 = fmaf(tv.x, wv.x, o0);
            o1 = fmaf(tv.y, wv.y, o1);
            o2 = fmaf(tv.z, wv.z, o2);
            o3 = fmaf(tv.w, wv.w, o3);
        }
        outp[(size_t)n * D + lane] = fmaxf((o0 + o1) + (o2 + o3), 0.0f);
    }
}

// ---------------------------------------------------------------------------
// Global mean pool over sorted batch[].
// ---------------------------------------------------------------------------
__device__ __forceinline__ int lower_bound_dev(const int* a, int n, int v)
{
    int lo = 0, hi = n;
    while (lo < hi) {
        int m = (lo + hi) >> 1;
        if (a[m] < v) lo = m + 1; else hi = m;
    }
    return lo;
}

__global__ __launch_bounds__(256) void pool_kernel(
    const float* __restrict__ feat,
    const int*   __restrict__ batch,
    float*       __restrict__ pooled)
{
    int b = blockIdx.x;
    int start = lower_bound_dev(batch, N_NODES, b);
    int end   = lower_bound_dev(batch, N_NODES, b + 1);

    int d = threadIdx.x & 63;
    int r = threadIdx.x >> 6;

    float acc = 0.0f;
    for (int n = start + r; n < end; n += 4)
        acc += feat[(size_t)n * D + d];

    __shared__ float red[4][D];
    red[r][d] = acc;
    __syncthreads();
    if (r == 0) {
        float s = red[0][d] + red[1][d] + red[2][d] + red[3][d];
        float cnt = (float)(end - start);
        pooled[b * D + d] = s / fmaxf(cnt, 1.0f);
    }
}

// ---------------------------------------------------------------------------
// Head: single-step LSTM + FC + softmax. One block (512 thr) per graph.
// ---------------------------------------------------------------------------
__device__ __forceinline__ float sigmoidf_(float x) { return 1.0f / (1.0f + expf(-x)); }

__global__ __launch_bounds__(512) void head_kernel(
    const float* __restrict__ pooled,
    const float* __restrict__ w_ih,
    const float* __restrict__ w_hh,
    const float* __restrict__ b_ih,
    const float* __restrict__ b_hh,
    const float* __restrict__ fc_w,
    const float* __restrict__ fc_b,
    const float* __restrict__ h0,
    const float* __restrict__ c0,
    float*       __restrict__ out_probs,
    float*       __restrict__ out_h1,
    float*       __restrict__ out_c1)
{
    int b = blockIdx.x;
    int j = threadIdx.x;

    __shared__ float sp[D];
    __shared__ float sh[HL];
    __shared__ float gates[4 * HL];
    __shared__ float sh1[HL];
    __shared__ float slog[OUT];

    if (j < D) sp[j] = pooled[b * D + j];
    else if (j < D + HL) sh[j - D] = h0[b * HL + (j - D)];
    __syncthreads();

    {
        float acc = b_ih[j] + b_hh[j];
#pragma unroll
        for (int k = 0; k < D; ++k)  acc = fmaf(sp[k], w_ih[j * D + k], acc);
#pragma unroll
        for (int k = 0; k < HL; ++k) acc = fmaf(sh[k], w_hh[j * HL + k], acc);
        gates[j] = acc;
    }
    __syncthreads();

    if (j < HL) {
        float ig = gates[j];
        float fg = gates[HL + j];
        float gg = gates[2 * HL + j];
        float og = gates[3 * HL + j];
        float c  = sigmoidf_(fg) * c0[b * HL + j] + sigmoidf_(ig) * tanhf(gg);
        float hv = sigmoidf_(og) * tanhf(c);
        out_c1[b * HL + j] = c;
        out_h1[b * HL + j] = hv;
        sh1[j] = hv;
    }
    __syncthreads();

    if (j < OUT) {
        float a = fc_b[j];
#pragma unroll
        for (int k = 0; k < HL; ++k) a = fmaf(sh1[k], fc_w[j * HL + k], a);
        slog[j] = a;
    }
    __syncthreads();

    if (j < OUT) {
        float m = -1e30f;
#pragma unroll
        for (int k = 0; k < OUT; ++k) m = fmaxf(m, slog[k]);
        float s = 0.0f;
#pragma unroll
        for (int k = 0; k < OUT; ++k) s += expf(slog[k] - m);
        out_probs[b * OUT + j] = expf(slog[j] - m) / s;
    }
}

// ---------------------------------------------------------------------------
extern "C" void kernel_launch(void* const* d_in, const int* in_sizes, int n_in,
                              void* d_out, int out_size, void* d_ws, size_t ws_size,
                              hipStream_t stream)
{
    const float* x     = (const float*)d_in[0];
    const int*   ei    = (const int*)  d_in[1];
    const int*   batch = (const int*)  d_in[2];
    const float* w1    = (const float*)d_in[3];
    const float* b1    = (const float*)d_in[4];
    const float* w2    = (const float*)d_in[5];
    const float* b2    = (const float*)d_in[6];
    const float* w3    = (const float*)d_in[7];
    const float* b3    = (const float*)d_in[8];
    const float* w4    = (const float*)d_in[9];
    const float* b4    = (const float*)d_in[10];
    const float* w_ih  = (const float*)d_in[11];
    const float* w_hh  = (const float*)d_in[12];
    const float* b_ih  = (const float*)d_in[13];
    const float* b_hh  = (const float*)d_in[14];
    const float* fc_w  = (const float*)d_in[15];
    const float* fc_b  = (const float*)d_in[16];
    const float* h0    = (const float*)d_in[17];
    const float* c0    = (const float*)d_in[18];

    // workspace layout (ints first, 16B-aligned float region after)
    int* deg    = (int*)d_ws;            // NPAD
    int* offs   = deg + NPAD;            // NPAD (uses N_NODES+1)
    int* cursor = offs + NPAD;           // NPAD
    int* bsum   = cursor + NPAD;         // 256
    int* bpre   = bsum + 256;            // 256
    int* csr    = bpre + 256;            // N_EDGES
    float* buf0   = (float*)(csr + N_EDGES);          // [N,64]
    float* buf1   = buf0 + (size_t)N_NODES * D;       // [N,64]
    float* pooled = buf1 + (size_t)N_NODES * D;       // [B,64]

    float* out_probs = (float*)d_out;
    float* out_h1    = out_probs + B * OUT;
    float* out_c1    = out_h1 + B * HL;

    const int eb = (N_EDGES + 255) / 256;       // 3125
    const int lb = (N_NODES + 15) / 16;         // 3125 (16 nodes per block)

    // ---- CSR build (dst-indexed) ----
    hipMemsetAsync(deg, 0, NPAD * sizeof(int), stream);
    hist_kernel<<<eb, 256, 0, stream>>>(ei, deg);
    scan_a_kernel<<<NB, 256, 0, stream>>>(deg, bsum);
    scan_b_kernel<<<1, 256, 0, stream>>>(bsum, bpre);
    scan_c_kernel<<<NB, 256, 0, stream>>>(deg, bpre, offs, cursor);
    fill_kernel<<<eb, 256, 0, stream>>>(ei, cursor, csr);

    // ---- layer 1 (fused gather + MLP) ----
    gin_layer_kernel<<<lb, 256, 0, stream>>>(x, offs, csr, w1, b1, w2, b2, buf1);

    // ---- layer 2 ----
    gin_layer_kernel<<<lb, 256, 0, stream>>>(buf1, offs, csr, w3, b3, w4, b4, buf0);

    // ---- pool + head ----
    pool_kernel<<<B, 256, 0, stream>>>(buf0, batch, pooled);
    head_kernel<<<B, 512, 0, stream>>>(pooled, w_ih, w_hh, b_ih, b_hh,
                                       fc_w, fc_b, h0, c0,
                                       out_probs, out_h1, out_c1);
}